// Round 11
// baseline (1168.986 us; speedup 1.0000x reference)
//
#include <hip/hip_runtime.h>
#include <hip/hip_bf16.h>

// QLSTM: SEQ=1024, B=64, D_IN=256, D_H=256, fp32 in/out.
// Phase 1: Xp = x @ Wx + bias (f16 MFMA GEMM), A-RESIDENT restructure: one WG per
//   128-row block stages A (128x256 f16) into LDS ONCE, loops all 8 col-blocks with
//   full-K 64KB B-tiles -> X read 1x (was 8x = 512MB A-traffic), B reads L3-hot.
//   Cols permuted j' = h*4+g (r10): epilogue stores contiguous, seq reads one f16x4.
// Phase 2 (r9/r10 shell): 64 WGs (1/batch), 1024 thr, 16 waves, 4/SIMD, i8 MFMA,
//   weights fully register-resident, ONE lds_barrier/step.
//   r11: tanh(x) = 1 - 2*rcp(exp(2x)+1) — 5 dep ops vs 8, clamp-free (inf/0 both
//   graceful) — 2 tanh on the serial cx-chain per step.
// Cycle model (r10: 2220 cyc/step measured): per-SIMD i8 MFMA issue floor = 64 x
//   ~20.4 cyc = 1305; rest = post-barrier ds_read latency (~150) + serial tail
//   (~250) + barrier skew. Lockstep is structural: every wave's step-t+1 read
//   depends on ALL waves' step-t writes. Seq floor ~= 1800 cyc ~= 770 us.
// prepmax+prepq fused: 4 WGs, LDS max-reduce over row-quarters, quantize in-kernel.
// r3/r7: cross-CU exchange dead. r6: all Wh crosses the MFMA B-port every step.
// r8: per-column i8 scales + i32 accum + hx@127 leave absmax unchanged (0.0039).

typedef _Float16 f16;
typedef _Float16 f16x4 __attribute__((ext_vector_type(4)));
typedef _Float16 f16x8 __attribute__((ext_vector_type(8)));
typedef float f32x4 __attribute__((ext_vector_type(4)));
typedef int i32x4 __attribute__((ext_vector_type(4)));

#define SEQ 1024
#define BATCH 64
#define DIN 256
#define DH 256
#define NCOL 1024

// ---- ws layout (bytes) ----
#define WXP_OFF   0u                 // f16 [32][1024][8], cols j'=h*4+g  = 524288
#define WHQ_OFF   524288u            // i8 tiles [16 w][4 g][4 kt][64][16] = 262144
#define SCL_OFF   786432u            // f32 [1024] final scale (s_j/127)
#define BIAS_OFF  790528u            // f32 [1024], j'-indexed
#define HXS8_OFF  794624u            // i8  [64][256]
#define CXS_OFF   811008u            // f32 [64][256]
#define XP_OFF    876544u            // f16 [Tc*64][256 h][4 g]

#define XPROJ_LDS 131584             // As 128*258*2 + Bs 32*128*8*2

__device__ __forceinline__ float fast_sigmoid(float x) {
  float e = __expf(-x);
  return __builtin_amdgcn_rcpf(1.0f + e);
}
// clamp-free tanh: 1 - 2/(e^{2x}+1). x>>0: e=inf -> rcp=0 -> 1; x<<0: e=0 -> -1.
__device__ __forceinline__ float fast_tanh(float x) {
  float e = __expf(2.0f * x);
  return fmaf(-2.0f, __builtin_amdgcn_rcpf(e + 1.0f), 1.0f);
}
// LDS-only barrier: no vmcnt drain (out-stores / Xp loads ride across).
__device__ __forceinline__ void lds_barrier() {
  asm volatile("s_waitcnt lgkmcnt(0)\n\ts_barrier" ::: "memory");
}
__device__ __forceinline__ i32x4 MQ(i32x4 a, i32x4 b, i32x4 c) {
  return __builtin_amdgcn_mfma_i32_16x16x64_i8(a, b, c, 0, 0, 0);
}

// ---------------- prep A: Wxp (f16, permuted cols) + bias ----------------
__global__ void qlstm_prep(const float* __restrict__ Wf, const float* __restrict__ Wi,
                           const float* __restrict__ Wg, const float* __restrict__ Wo,
                           const float* __restrict__ bf_, const float* __restrict__ bi_,
                           const float* __restrict__ bg_, const float* __restrict__ bo_,
                           f16* __restrict__ Wxp, float* __restrict__ biasp) {
  int tid = blockIdx.x * 256 + threadIdx.x;
  if (tid < 4 * 256 * 256) {
    int g = tid >> 16;
    int rem = tid & 65535;
    int k = rem >> 8, n = rem & 255;           // k < 256: x-rows only
    const float* W = (g == 0) ? Wf : (g == 1) ? Wi : (g == 2) ? Wg : Wo;
    float v = W[k * 256 + n];
    int j = n * 4 + g;                         // PERMUTED column
    Wxp[((size_t)(k >> 3) * 1024 + j) * 8 + (k & 7)] = (f16)v;
  }
  if (tid < 1024) {
    int g = tid >> 8, n = tid & 255;
    const float* bb = (g == 0) ? bf_ : (g == 1) ? bi_ : (g == 2) ? bg_ : bo_;
    biasp[n * 4 + g] = bb[n];                  // PERMUTED bias
  }
}

// ---------------- prep B: fused colmax + i8 quantize (4 WGs, 1 per gate) ----------------
__global__ __launch_bounds__(1024) void qlstm_prepq(
    const float* __restrict__ Wf, const float* __restrict__ Wi,
    const float* __restrict__ Wg, const float* __restrict__ Wo,
    char* __restrict__ WhQ, float* __restrict__ scl) {
  __shared__ float red[4][256];
  int g = blockIdx.x;
  int tid = threadIdx.x, q = tid >> 8, n = tid & 255;
  const float* W = (g == 0) ? Wf : (g == 1) ? Wi : (g == 2) ? Wg : Wo;

  float pm = 0.0f;
  for (int r = 0; r < 64; ++r)                 // coalesced: 4 rows x 1KB per iter
    pm = fmaxf(pm, fabsf(W[(size_t)(256 + q * 64 + r) * 256 + n]));
  red[q][n] = pm;
  __syncthreads();
  float mx = fmaxf(fmaxf(red[0][n], red[1][n]), fmaxf(red[2][n], red[3][n]));
  float s = (mx > 0.0f) ? mx * (1.0f / 127.0f) : 1.0f;
  float inv = 1.0f / s;

  int w = n >> 4, c = n & 15;
  for (int rr = 0; rr < 64; ++rr) {            // L2-hot re-read, quantize
    int r = q * 64 + rr;
    float v = W[(size_t)(256 + r) * 256 + n];
    int qv = (int)rintf(v * inv);
    qv = qv > 127 ? 127 : (qv < -127 ? -127 : qv);
    int kt = r >> 6, kp = r & 63;
    int lane = (kp >> 4) * 16 + c, jj = kp & 15;
    WhQ[((size_t)((w * 16 + g * 4 + kt) * 64 + lane)) * 16 + jj] = (char)qv;
  }
  if (q == 0) scl[g * 256 + n] = s * (1.0f / 127.0f);
}

// ---------------- phase 1: Xp = x @ Wx + bias (A-resident MFMA f16) ----------------
__global__ __launch_bounds__(256) void qlstm_xproj(
    const float* __restrict__ X, const f16* __restrict__ Wxp,
    const float* __restrict__ biasp, f16* __restrict__ Xp2) {
  extern __shared__ char smem[];
  f16* As = (f16*)smem;                        // [128][258] (pad: stride 516B ≡ 1 bank)
  f16* Bs = (f16*)(smem + 66048);              // [32 kg][128 col][8]

  int tid = threadIdx.x;
  int tm = blockIdx.x;
  int wave = tid >> 6, lane = tid & 63;
  int qm = (wave & 1) * 64, qn = (wave >> 1) * 64;
  int lm = lane & 15, lk = lane >> 4;

  // stage A ONCE: 128 rows x 256 k, f32 -> f16
  {
    int r = tid >> 1, c0 = (tid & 1) * 128;
    const float4* src = (const float4*)(X + (size_t)(tm * 128 + r) * 256 + c0);
#pragma unroll
    for (int i = 0; i < 32; ++i) {
      float4 v = src[i];
      f16x4 pk = {(f16)v.x, (f16)v.y, (f16)v.z, (f16)v.w};
      *(f16x4*)&As[r * 258 + c0 + i * 4] = pk;
    }
  }

  for (int tn = 0; tn < 8; ++tn) {
    __syncthreads();                           // protect Bs (and As on tn=0)
    {
#pragma unroll
      for (int it = 0; it < 16; ++it) {
        int idx = it * 256 + tid;              // 0..4095
        int kg = idx >> 7, n = idx & 127;
        ((uint4*)Bs)[idx] =
            *(const uint4*)(Wxp + ((size_t)kg * 1024 + tn * 128 + n) * 8);
      }
    }
    __syncthreads();

    f32x4 acc[4][4];
#pragma unroll
    for (int a = 0; a < 4; ++a)
#pragma unroll
      for (int b = 0; b < 4; ++b) acc[a][b] = (f32x4)0.0f;

#pragma unroll
    for (int k0 = 0; k0 < 256; k0 += 64) {
#pragma unroll
      for (int ks = 0; ks < 2; ++ks) {
        f16x8 af[4], bfr[4];
        int kgab = (k0 >> 3) + ks * 4 + lk;
#pragma unroll
        for (int mi = 0; mi < 4; ++mi)
          af[mi] = *(const f16x8*)&As[(qm + mi * 16 + lm) * 258 + k0 + ks * 32 + lk * 8];
#pragma unroll
        for (int ni = 0; ni < 4; ++ni)
          bfr[ni] = *(const f16x8*)&Bs[((size_t)kgab * 128 + qn + ni * 16 + lm) * 8];
#pragma unroll
        for (int mi = 0; mi < 4; ++mi)
#pragma unroll
          for (int ni = 0; ni < 4; ++ni)
            acc[mi][ni] = __builtin_amdgcn_mfma_f32_16x16x32_f16(af[mi], bfr[ni],
                                                                 acc[mi][ni], 0, 0, 0);
      }
    }

    // epilogue for this col-block: j' layout -> contiguous f16 runs
    int m0 = tm * 128 + qm, j0 = tn * 128 + qn;
#pragma unroll
    for (int mi = 0; mi < 4; ++mi)
#pragma unroll
      for (int ni = 0; ni < 4; ++ni) {
        int j = j0 + ni * 16 + lm;
        float bv = biasp[j];
#pragma unroll
        for (int r = 0; r < 4; ++r) {
          int m = m0 + mi * 16 + lk * 4 + r;
          Xp2[(size_t)m * 1024 + j] = (f16)(acc[mi][ni][r] + bv);
        }
      }
  }
}

// ---------------- phase 2: sequential LSTM, i8 MFMA, 16 waves ----------------
__global__ __launch_bounds__(1024, 4) void qlstm_seq(
    const f16* __restrict__ Xp2, const i32x4* __restrict__ WhQ,
    const float* __restrict__ scl,
    float* __restrict__ out, char* __restrict__ hxs8, float* __restrict__ cxs,
    float* __restrict__ hxout, float* __restrict__ cxout, int t0, int t1) {
  __shared__ char hxq[2][256];                 // i8 hidden state, natural order

  int tid = threadIdx.x;
  int wv = tid >> 6, lane = tid & 63, c = lane & 15;
  int b = blockIdx.x;
  int h = wv * 16 + c;                         // my h column (all 4 gates)

  // weights: 4 gates x 4 kt tiles, 16B/lane = 64 regs (VGPR/AGPR; MFMA reads both)
  i32x4 wq[4][4];
  {
    const i32x4* wp = WhQ + (size_t)(wv * 16) * 64 + lane;
#pragma unroll
    for (int g = 0; g < 4; ++g)
#pragma unroll
      for (int kt = 0; kt < 4; ++kt) wq[g][kt] = wp[(g * 4 + kt) * 64];
  }
  float sc[4];
#pragma unroll
  for (int g = 0; g < 4; ++g) sc[g] = scl[g * 256 + h];

  int par0 = t0 & 1;
  if (tid < 16) {
    uint4 v;
    if (t0 == 0) v = uint4{0u, 0u, 0u, 0u};
    else v = ((const uint4*)(hxs8 + (size_t)b * 256))[tid];
    *(uint4*)(&hxq[par0][tid * 16]) = v;
  }
  float cx = (t0 != 0) ? cxs[(size_t)b * 256 + h] : 0.0f;

  __syncthreads();

  int koff = (lane >> 4) << 4;                 // A-frag k-chunk byte offset
  float hv = 0.0f;
  for (int t = t0; t < t1; ++t) {
    int par = t & 1, parn = par ^ 1;
    const char* hp = &hxq[par][0];

    // Xp: ONE 8B load = f16x4 of my 4 gate pre-projections (rides vmcnt)
    uint2 xr = *(const uint2*)(Xp2 + (((size_t)(t - t0) * BATCH + b) * 256 + h) * 4);

    // all 4 A-frags upfront: no mid-MFMA-phase lgkmcnt stalls
    i32x4 a0 = *(const i32x4*)(hp + koff);
    i32x4 a1 = *(const i32x4*)(hp + 64 + koff);
    i32x4 a2 = *(const i32x4*)(hp + 128 + koff);
    i32x4 a3 = *(const i32x4*)(hp + 192 + koff);

    i32x4 acc0{}, acc1{}, acc2{}, acc3{};
    acc0 = MQ(a0, wq[0][0], acc0); acc1 = MQ(a0, wq[1][0], acc1);
    acc2 = MQ(a0, wq[2][0], acc2); acc3 = MQ(a0, wq[3][0], acc3);
    acc0 = MQ(a1, wq[0][1], acc0); acc1 = MQ(a1, wq[1][1], acc1);
    acc2 = MQ(a1, wq[2][1], acc2); acc3 = MQ(a1, wq[3][1], acc3);
    acc0 = MQ(a2, wq[0][2], acc0); acc1 = MQ(a2, wq[1][2], acc1);
    acc2 = MQ(a2, wq[2][2], acc2); acc3 = MQ(a2, wq[3][2], acc3);
    acc0 = MQ(a3, wq[0][3], acc0); acc1 = MQ(a3, wq[1][3], acc1);
    acc2 = MQ(a3, wq[2][3], acc2); acc3 = MQ(a3, wq[3][3], acc3);

    // A broadcast => every lane's reg0 = its column's dot; dequant + x-proj
    f16x4 xh = __builtin_bit_cast(f16x4, xr);
    float p0 = fmaf((float)acc0[0], sc[0], (float)xh[0]);
    float p1 = fmaf((float)acc1[0], sc[1], (float)xh[1]);
    float p2 = fmaf((float)acc2[0], sc[2], (float)xh[2]);
    float p3 = fmaf((float)acc3[0], sc[3], (float)xh[3]);

    float vf = fast_sigmoid(p0);
    float vi = fast_sigmoid(p1);
    float vg = fast_tanh(p2);
    float vo = fast_sigmoid(p3);
    cx = fmaf(vf, cx, vi * vg);
    hv = vo * fast_tanh(cx);

    if (lane < 16) {
      hxq[parn][h] = (char)(int)rintf(hv * 127.0f);     // LDS write first
      out[((size_t)t * BATCH + b) * 256 + h] = hv;      // rides vmcnt
    }
    lds_barrier();                             // lgkmcnt(0)+s_barrier only
  }

  // persist state across chunk launches (exact i8 state + f32 cx)
  if (tid < 16)
    ((uint4*)(hxs8 + (size_t)b * 256))[tid] = *(const uint4*)(&hxq[t1 & 1][tid * 16]);
  if (lane < 16) {
    cxs[(size_t)b * 256 + h] = cx;
    if (t1 == SEQ) {
      hxout[(size_t)b * 256 + h] = hv;
      cxout[(size_t)b * 256 + h] = cx;
    }
  }
}

extern "C" void kernel_launch(void* const* d_in, const int* in_sizes, int n_in,
                              void* d_out, int out_size, void* d_ws, size_t ws_size,
                              hipStream_t stream) {
  const float* X  = (const float*)d_in[0];
  const float* Wf = (const float*)d_in[1]; const float* bf_ = (const float*)d_in[2];
  const float* Wi = (const float*)d_in[3]; const float* bi_ = (const float*)d_in[4];
  const float* Wg = (const float*)d_in[5]; const float* bg_ = (const float*)d_in[6];
  const float* Wo = (const float*)d_in[7]; const float* bo_ = (const float*)d_in[8];
  float* out = (float*)d_out;

  char* ws = (char*)d_ws;
  f16*   Wxp   = (f16*)(ws + WXP_OFF);
  char*  WhQ   = (char*)(ws + WHQ_OFF);
  float* scl   = (float*)(ws + SCL_OFF);
  float* biasp = (float*)(ws + BIAS_OFF);
  char*  hxs8  = (char*)(ws + HXS8_OFF);
  float* cxs   = (float*)(ws + CXS_OFF);
  f16*   Xp2   = (f16*)(ws + XP_OFF);

  size_t avail = (ws_size > XP_OFF) ? (ws_size - XP_OFF) : 0;
  int Tc = SEQ;
  while (Tc > 2 && (size_t)Tc * BATCH * NCOL * 2 > avail) Tc >>= 1;

  qlstm_prep<<<1024, 256, 0, stream>>>(Wf, Wi, Wg, Wo, bf_, bi_, bg_, bo_,
                                       Wxp, biasp);
  qlstm_prepq<<<4, 1024, 0, stream>>>(Wf, Wi, Wg, Wo, WhQ, scl);

  (void)hipFuncSetAttribute((const void*)qlstm_xproj,
                            hipFuncAttributeMaxDynamicSharedMemorySize,
                            XPROJ_LDS);

  float* hxout = out + (size_t)SEQ * BATCH * DH;
  float* cxout = hxout + BATCH * DH;

  for (int t0 = 0; t0 < SEQ; t0 += Tc) {
    qlstm_xproj<<<Tc * 64 / 128, 256, XPROJ_LDS, stream>>>(
        X + (size_t)t0 * BATCH * DIN, Wxp, biasp, Xp2);
    qlstm_seq<<<BATCH, 1024, 0, stream>>>(Xp2, (const i32x4*)WhQ, scl, out, hxs8, cxs,
                                          hxout, cxout, t0, t0 + Tc);
  }
}